// Round 8
// baseline (166.342 us; speedup 1.0000x reference)
//
#include <hip/hip_runtime.h>

#define NP      4096
#define WINDOW  327
#define HALF    163
#define RL      20
#define NA      262144
#define GN_EPS  1e-6f

// fast tanh: 1 - 2/(e^{2x}+1), ~1e-7 abs err
__device__ __forceinline__ float tanh_fast(float x) {
  float e = __expf(2.0f * x);
  return 1.0f - 2.0f / (e + 1.0f);
}

// butterfly sum over 32-lane groups
__device__ __forceinline__ void halfwave_sum2(float& a, float& b) {
#pragma unroll
  for (int m = 1; m < 32; m <<= 1) {
    a += __shfl_xor(a, m, 64);
    b += __shfl_xor(b, m, 64);
  }
}

// ---------------- K1: obs resize (16 rows/block, 256 blocks) ----------------
#define OBR 16
__global__ __launch_bounds__(256) void dc_obs(
    const float* __restrict__ zc, const float* __restrict__ zt,
    float* __restrict__ obsg)
{
  __shared__ float ewin[OBR + WINDOW - 1 + 2];   // 344
  const int tid = threadIdx.x;
  const int s0  = blockIdx.x * OBR;

  for (int t = tid; t < OBR + WINDOW - 1; t += 256) {
    int c = s0 - HALF + t;
    c = c < 0 ? 0 : (c > NP - 1 ? NP - 1 : c);
    ewin[t] = zc[c] - zt[c];
  }
  __syncthreads();

  const float INV  = (float)WINDOW / (float)RL;   // 16.35
  const float RINV = (float)RL / (float)WINDOW;
  for (int task = tid; task < OBR * 2 * RL; task += 256) {  // 640 tasks
    int q = task % (2 * RL);
    int r = task / (2 * RL);
    int qq = (q < RL) ? q : q - RL;
    float xs = ((float)qq + 0.5f) * INV - 0.5f;
    int jlo = (int)ceilf(xs - INV);  if (jlo < 0) jlo = 0;
    int jhi = (int)floorf(xs + INV); if (jhi > WINDOW - 1) jhi = WINDOW - 1;
    const float* p = ewin + r;
    float wsum = 0.0f, acc = 0.0f;
    for (int j = jlo; j <= jhi; ++j) {
      float wq = 1.0f - fabsf(xs - (float)j) * RINV;
      float v;
      if (q < RL) {
        v = p[j];
      } else {  // jnp.gradient on the window
        v = (j == 0) ? (p[1] - p[0]) :
            (j == WINDOW - 1) ? (p[WINDOW - 1] - p[WINDOW - 2]) :
            0.5f * (p[j + 1] - p[j - 1]);
      }
      wsum += wq;
      acc  += wq * v;
    }
    obsg[(s0 + r) * 40 + q] = acc / wsum;
  }
}

// ---------------- K2: branch net (8 rows/block, 512 blocks) ----------------
#define R 8
// LDS: obsT[40][8]=320 + hbuf[8][260]=2080 + part[4][8][256]=8192 = 10592 fl = 42.4 KB -> 3 blk/CU
#define L_OBS   0
#define L_HBUF  320
#define L_PART  2400
#define L_TOT   10592

__global__ __launch_bounds__(256, 3) void dc_net(
    const float* __restrict__ obsg,
    const float* __restrict__ bW0, const float* __restrict__ bb0,
    const float* __restrict__ bs0, const float* __restrict__ bB0,
    const float* __restrict__ bW1, const float* __restrict__ bb1,
    const float* __restrict__ bs1, const float* __restrict__ bB1,
    const float* __restrict__ cW,  const float* __restrict__ cb,
    float* __restrict__ hc)
{
  __shared__ __align__(16) float sm[L_TOT];
  float* obsT = sm + L_OBS;    // [k][r], stride 8
  float* hbuf = sm + L_HBUF;   // [r][f], stride 260
  float* part = sm + L_PART;   // [w][r][f]

  const int tid = threadIdx.x;
  const int w   = tid >> 6;
  const int l   = tid & 63;
  const int rG  = tid >> 5;
  const int cG  = tid & 31;
  const int s0  = blockIdx.x * R;

  // prefetch layer-0 first weight row; then load+transpose obs
  const float* w0p = bW0 + (w * 10) * 256 + 4 * l;
  float4 wt0_n = *(const float4*)w0p;

  if (tid < 80) {
    int r = tid / 10, qd = tid % 10;
    float4 v = *(const float4*)&obsg[(s0 + r) * 40 + 4 * qd];
    int k0 = 4 * qd;
    obsT[(k0    ) * 8 + r] = v.x;
    obsT[(k0 + 1) * 8 + r] = v.y;
    obsT[(k0 + 2) * 8 + r] = v.z;
    obsT[(k0 + 3) * 8 + r] = v.w;
  }
  __syncthreads();

  float acc[R][4];

  // ---- Layer 0 (40 -> 256), k-split 4-way, 1-deep prefetch ----
#pragma unroll
  for (int r = 0; r < R; ++r) { acc[r][0]=0.f; acc[r][1]=0.f; acc[r][2]=0.f; acc[r][3]=0.f; }
#pragma unroll
  for (int kk = 0; kk < 10; ++kk) {
    float4 wt = wt0_n;
    if (kk < 9) wt0_n = *(const float4*)(w0p + (kk + 1) * 256);
    int k = w * 10 + kk;
    float4 o0 = *(const float4*)&obsT[k * 8];
    float4 o1 = *(const float4*)&obsT[k * 8 + 4];
    const float os[8] = {o0.x, o0.y, o0.z, o0.w, o1.x, o1.y, o1.z, o1.w};
    const float wv[4] = {wt.x, wt.y, wt.z, wt.w};
#pragma unroll
    for (int r = 0; r < R; ++r)
#pragma unroll
      for (int j = 0; j < 4; ++j) acc[r][j] = fmaf(os[r], wv[j], acc[r][j]);
  }
#pragma unroll
  for (int r = 0; r < R; ++r)
    *(float4*)&part[w * 2048 + r * 256 + 4 * l] = make_float4(acc[r][0], acc[r][1], acc[r][2], acc[r][3]);
  __syncthreads();

  // ---- GN0 + tanh (prefetch layer-1 first 4 weight rows during it) ----
  const float* w1p = bW1 + (w * 64) * 256 + 4 * l;
  float4 wt_n0 = *(const float4*)(w1p);
  float4 wt_n1 = *(const float4*)(w1p + 256);
  float4 wt_n2 = *(const float4*)(w1p + 512);
  float4 wt_n3 = *(const float4*)(w1p + 768);
  {
    float val[8];
    {
      float4 b0 = *(const float4*)&bb0[8 * cG];
      float4 b1 = *(const float4*)&bb0[8 * cG + 4];
      val[0]=b0.x; val[1]=b0.y; val[2]=b0.z; val[3]=b0.w;
      val[4]=b1.x; val[5]=b1.y; val[6]=b1.z; val[7]=b1.w;
    }
#pragma unroll
    for (int w2 = 0; w2 < 4; ++w2) {
      float4 p0 = *(const float4*)&part[w2 * 2048 + rG * 256 + 8 * cG];
      float4 p1 = *(const float4*)&part[w2 * 2048 + rG * 256 + 8 * cG + 4];
      val[0]+=p0.x; val[1]+=p0.y; val[2]+=p0.z; val[3]+=p0.w;
      val[4]+=p1.x; val[5]+=p1.y; val[6]+=p1.z; val[7]+=p1.w;
    }
    float s = 0.f, q = 0.f;
#pragma unroll
    for (int i = 0; i < 8; ++i) { s += val[i]; q += val[i] * val[i]; }
    halfwave_sum2(s, q);
    float mu  = s * (1.0f / 256.0f);
    float var = fmaxf(q * (1.0f / 256.0f) - mu * mu, 0.0f);
    float rv  = rsqrtf(var + GN_EPS);
    float4 sc0 = *(const float4*)&bs0[8 * cG];
    float4 sc1 = *(const float4*)&bs0[8 * cG + 4];
    float4 sh0 = *(const float4*)&bB0[8 * cG];
    float4 sh1 = *(const float4*)&bB0[8 * cG + 4];
    const float sc[8] = {sc0.x,sc0.y,sc0.z,sc0.w,sc1.x,sc1.y,sc1.z,sc1.w};
    const float sh[8] = {sh0.x,sh0.y,sh0.z,sh0.w,sh1.x,sh1.y,sh1.z,sh1.w};
    float h[8];
#pragma unroll
    for (int i = 0; i < 8; ++i) h[i] = tanh_fast((val[i] - mu) * rv * sc[i] + sh[i]);
    *(float4*)&hbuf[rG * 260 + 8 * cG]     = make_float4(h[0], h[1], h[2], h[3]);
    *(float4*)&hbuf[rG * 260 + 8 * cG + 4] = make_float4(h[4], h[5], h[6], h[7]);
  }
  __syncthreads();

  // ---- Layer 1 (256 -> 256), k-split 4-way, 4-row prefetch ----
#pragma unroll
  for (int r = 0; r < R; ++r) { acc[r][0]=0.f; acc[r][1]=0.f; acc[r][2]=0.f; acc[r][3]=0.f; }
  for (int kk = 0; kk < 64; kk += 4) {
    float4 wt0 = wt_n0, wt1 = wt_n1, wt2 = wt_n2, wt3 = wt_n3;
    if (kk < 60) {
      wt_n0 = *(const float4*)(w1p + (kk + 4) * 256);
      wt_n1 = *(const float4*)(w1p + (kk + 5) * 256);
      wt_n2 = *(const float4*)(w1p + (kk + 6) * 256);
      wt_n3 = *(const float4*)(w1p + (kk + 7) * 256);
    }
    int k0 = w * 64 + kk;
#pragma unroll
    for (int r = 0; r < R; ++r) {
      float4 hv = *(const float4*)&hbuf[r * 260 + k0];
      acc[r][0] = fmaf(hv.x, wt0.x, acc[r][0]); acc[r][1] = fmaf(hv.x, wt0.y, acc[r][1]);
      acc[r][2] = fmaf(hv.x, wt0.z, acc[r][2]); acc[r][3] = fmaf(hv.x, wt0.w, acc[r][3]);
      acc[r][0] = fmaf(hv.y, wt1.x, acc[r][0]); acc[r][1] = fmaf(hv.y, wt1.y, acc[r][1]);
      acc[r][2] = fmaf(hv.y, wt1.z, acc[r][2]); acc[r][3] = fmaf(hv.y, wt1.w, acc[r][3]);
      acc[r][0] = fmaf(hv.z, wt2.x, acc[r][0]); acc[r][1] = fmaf(hv.z, wt2.y, acc[r][1]);
      acc[r][2] = fmaf(hv.z, wt2.z, acc[r][2]); acc[r][3] = fmaf(hv.z, wt2.w, acc[r][3]);
      acc[r][0] = fmaf(hv.w, wt3.x, acc[r][0]); acc[r][1] = fmaf(hv.w, wt3.y, acc[r][1]);
      acc[r][2] = fmaf(hv.w, wt3.z, acc[r][2]); acc[r][3] = fmaf(hv.w, wt3.w, acc[r][3]);
    }
  }
#pragma unroll
  for (int r = 0; r < R; ++r)
    *(float4*)&part[w * 2048 + r * 256 + 4 * l] = make_float4(acc[r][0], acc[r][1], acc[r][2], acc[r][3]);
  __syncthreads();

  // ---- GN1 + tanh -> hbuf (prefetch cb + first cW chunk during it) ----
  float cbv = cb[cG];
  const float* cwp = cW + cG;
  float cwn[8];
#pragma unroll
  for (int i = 0; i < 8; ++i) cwn[i] = cwp[i * 32];
  {
    float val[8];
    {
      float4 b0 = *(const float4*)&bb1[8 * cG];
      float4 b1 = *(const float4*)&bb1[8 * cG + 4];
      val[0]=b0.x; val[1]=b0.y; val[2]=b0.z; val[3]=b0.w;
      val[4]=b1.x; val[5]=b1.y; val[6]=b1.z; val[7]=b1.w;
    }
#pragma unroll
    for (int w2 = 0; w2 < 4; ++w2) {
      float4 p0 = *(const float4*)&part[w2 * 2048 + rG * 256 + 8 * cG];
      float4 p1 = *(const float4*)&part[w2 * 2048 + rG * 256 + 8 * cG + 4];
      val[0]+=p0.x; val[1]+=p0.y; val[2]+=p0.z; val[3]+=p0.w;
      val[4]+=p1.x; val[5]+=p1.y; val[6]+=p1.z; val[7]+=p1.w;
    }
    float s = 0.f, q = 0.f;
#pragma unroll
    for (int i = 0; i < 8; ++i) { s += val[i]; q += val[i] * val[i]; }
    halfwave_sum2(s, q);
    float mu  = s * (1.0f / 256.0f);
    float var = fmaxf(q * (1.0f / 256.0f) - mu * mu, 0.0f);
    float rv  = rsqrtf(var + GN_EPS);
    float4 sc0 = *(const float4*)&bs1[8 * cG];
    float4 sc1 = *(const float4*)&bs1[8 * cG + 4];
    float4 sh0 = *(const float4*)&bB1[8 * cG];
    float4 sh1 = *(const float4*)&bB1[8 * cG + 4];
    const float sc[8] = {sc0.x,sc0.y,sc0.z,sc0.w,sc1.x,sc1.y,sc1.z,sc1.w};
    const float sh[8] = {sh0.x,sh0.y,sh0.z,sh0.w,sh1.x,sh1.y,sh1.z,sh1.w};
    float h[8];
#pragma unroll
    for (int i = 0; i < 8; ++i) h[i] = tanh_fast((val[i] - mu) * rv * sc[i] + sh[i]);
    *(float4*)&hbuf[rG * 260 + 8 * cG]     = make_float4(h[0], h[1], h[2], h[3]);
    *(float4*)&hbuf[rG * 260 + 8 * cG + 4] = make_float4(h[4], h[5], h[6], h[7]);
  }
  __syncthreads();

  // ---- Phase G: hc[(s0+rG)*32+cG] = cb + h1[rG,:].cW[:,cG], 8-deep prefetch ----
  {
    float ga = 0.0f;
    for (int k = 0; k < 256; k += 8) {
      float cw0=cwn[0], cw1=cwn[1], cw2=cwn[2], cw3=cwn[3];
      float cw4=cwn[4], cw5=cwn[5], cw6=cwn[6], cw7=cwn[7];
      if (k < 248) {
#pragma unroll
        for (int i = 0; i < 8; ++i) cwn[i] = cwp[(k + 8 + i) * 32];
      }
      float4 h0 = *(const float4*)&hbuf[rG * 260 + k];
      float4 h1 = *(const float4*)&hbuf[rG * 260 + k + 4];
      ga = fmaf(h0.x, cw0, ga); ga = fmaf(h0.y, cw1, ga);
      ga = fmaf(h0.z, cw2, ga); ga = fmaf(h0.w, cw3, ga);
      ga = fmaf(h1.x, cw4, ga); ga = fmaf(h1.y, cw5, ga);
      ga = fmaf(h1.z, cw6, ga); ga = fmaf(h1.w, cw7, ga);
    }
    hc[(s0 + rG) * 32 + cG] = ga + cbv;
  }
}

// ---------------- K3: endpoint evals (16 bins/block, 256 blocks) ----------------
__global__ __launch_bounds__(256) void dc_tail(
    const float* __restrict__ hc,
    const float* __restrict__ tW0, const float* __restrict__ tb0,
    const float* __restrict__ tW1, const float* __restrict__ tb1,
    const float* __restrict__ cW,
    const float* __restrict__ uW,  const float* __restrict__ ub,
    const float* __restrict__ vW,  const float* __restrict__ vb,
    float* __restrict__ tbl)
{
  const int tid = threadIdx.x;
  const int v   = tid >> 3;        // 0..31: bin-rel*2 + endpoint
  const int sub = tid & 7;
  const int r   = v >> 1, e = v & 1;
  const int s   = blockIdx.x * 16 + r;
  const int jg  = s + e;
  const int base = (tid & 63) & ~7;

  float xe = (float)jg * (1.0f / 4095.0f);
  float enc[8];
#pragma unroll
  for (int k = 0; k < 4; ++k) {
    float fr = (float)(1 << k);
    float a = (xe * fr) * 3.14159265358979f;
    enc[k]     = sinf(a);
    enc[k + 4] = cosf(a);
  }

  float t0v[4];
  {
    float4 b = *(const float4*)&tb0[4 * sub];
    t0v[0]=b.x; t0v[1]=b.y; t0v[2]=b.z; t0v[3]=b.w;
  }
#pragma unroll
  for (int k = 0; k < 8; ++k) {
    float4 wq = *(const float4*)&tW0[k * 32 + 4 * sub];
    t0v[0] = fmaf(enc[k], wq.x, t0v[0]);
    t0v[1] = fmaf(enc[k], wq.y, t0v[1]);
    t0v[2] = fmaf(enc[k], wq.z, t0v[2]);
    t0v[3] = fmaf(enc[k], wq.w, t0v[3]);
  }
#pragma unroll
  for (int i = 0; i < 4; ++i) t0v[i] = tanh_fast(t0v[i]);

  float t1v[4];
  {
    float4 b = *(const float4*)&tb1[4 * sub];
    t1v[0]=b.x; t1v[1]=b.y; t1v[2]=b.z; t1v[3]=b.w;
  }
#pragma unroll
  for (int j8 = 0; j8 < 8; ++j8) {
#pragma unroll
    for (int i2 = 0; i2 < 4; ++i2) {
      float tv = __shfl(t0v[i2], base + j8, 64);
      float4 wq = *(const float4*)&tW1[(4 * j8 + i2) * 32 + 4 * sub];
      t1v[0] = fmaf(tv, wq.x, t1v[0]);
      t1v[1] = fmaf(tv, wq.y, t1v[1]);
      t1v[2] = fmaf(tv, wq.z, t1v[2]);
      t1v[3] = fmaf(tv, wq.w, t1v[3]);
    }
  }
#pragma unroll
  for (int i = 0; i < 4; ++i) t1v[i] = tanh_fast(t1v[i]);

  float xvv[4];
  {
    float4 hq = *(const float4*)&hc[s * 32 + 4 * sub];
    xvv[0]=hq.x; xvv[1]=hq.y; xvv[2]=hq.z; xvv[3]=hq.w;
  }
#pragma unroll
  for (int j8 = 0; j8 < 8; ++j8) {
#pragma unroll
    for (int i2 = 0; i2 < 4; ++i2) {
      float tv = __shfl(t1v[i2], base + j8, 64);
      float4 wq = *(const float4*)&cW[(256 + 4 * j8 + i2) * 32 + 4 * sub];
      xvv[0] = fmaf(tv, wq.x, xvv[0]);
      xvv[1] = fmaf(tv, wq.y, xvv[1]);
      xvv[2] = fmaf(tv, wq.z, xvv[2]);
      xvv[3] = fmaf(tv, wq.w, xvv[3]);
    }
  }
#pragma unroll
  for (int i = 0; i < 4; ++i) xvv[i] = tanh_fast(xvv[i]);

  float4 wu = *(const float4*)&uW[4 * sub];
  float4 wv = *(const float4*)&vW[4 * sub];
  float up = xvv[0]*wu.x + xvv[1]*wu.y + xvv[2]*wu.z + xvv[3]*wu.w;
  float vp = xvv[0]*wv.x + xvv[1]*wv.y + xvv[2]*wv.z + xvv[3]*wv.w;
#pragma unroll
  for (int m = 1; m < 8; m <<= 1) {
    up += __shfl_xor(up, m, 64);
    vp += __shfl_xor(vp, m, 64);
  }
  if (sub == 0) {
    tbl[4 * s + e]     = 40.0f * tanh_fast(up + ub[0]);
    tbl[4 * s + 2 + e] = tanh_fast(vp + vb[0]);
  }
}

// ---------------- K4: agents = bin + lerp ----------------
__global__ __launch_bounds__(256) void dc_agents(
    const float* __restrict__ xi_curr, const float4* __restrict__ tbl,
    float* __restrict__ out)
{
  int a = blockIdx.x * 256 + threadIdx.x;
  float xi = xi_curr[a];
  float p = xi * 4095.0f;           // same fp32 product the reference truncates
  int s = (int)p;
  s = s > 4095 ? 4095 : s;
  float t = p - (float)s;           // exact (Sterbenz)
  float4 tb = tbl[s];               // {u_l, u_r, v_l, v_r}
  out[a]      = fmaf(t, tb.y - tb.x, tb.x);
  out[NA + a] = fmaf(t, tb.w - tb.z, tb.z);
}

extern "C" void kernel_launch(void* const* d_in, const int* in_sizes, int n_in,
                              void* d_out, int out_size, void* d_ws, size_t ws_size,
                              hipStream_t stream) {
  const float* zc  = (const float*)d_in[0];
  const float* zt  = (const float*)d_in[1];
  const float* xi  = (const float*)d_in[2];
  const float* bW0 = (const float*)d_in[3];
  const float* bb0 = (const float*)d_in[4];
  const float* bs0 = (const float*)d_in[5];
  const float* bB0 = (const float*)d_in[6];
  const float* bW1 = (const float*)d_in[7];
  const float* bb1 = (const float*)d_in[8];
  const float* bs1 = (const float*)d_in[9];
  const float* bB1 = (const float*)d_in[10];
  const float* tW0 = (const float*)d_in[11];
  const float* tb0 = (const float*)d_in[12];
  const float* tW1 = (const float*)d_in[13];
  const float* tb1 = (const float*)d_in[14];
  const float* cW  = (const float*)d_in[15];
  const float* cb  = (const float*)d_in[16];
  const float* uW  = (const float*)d_in[17];
  const float* ub  = (const float*)d_in[18];
  const float* vW  = (const float*)d_in[19];
  const float* vb  = (const float*)d_in[20];

  float* tbl  = (float*)d_ws;                 // 4096 x 4
  float* hc   = (float*)d_ws + 16384;         // 4096 x 32
  float* obsg = (float*)d_ws + 16384 + 131072;// 4096 x 40

  dc_obs<<<NP / OBR, 256, 0, stream>>>(zc, zt, obsg);
  dc_net<<<NP / R, 256, 0, stream>>>(obsg, bW0, bb0, bs0, bB0,
                                     bW1, bb1, bs1, bB1, cW, cb, hc);
  dc_tail<<<NP / 16, 256, 0, stream>>>(hc, tW0, tb0, tW1, tb1, cW,
                                       uW, ub, vW, vb, tbl);
  dc_agents<<<NA / 256, 256, 0, stream>>>(xi, (const float4*)tbl, (float*)d_out);
}